// Round 11
// baseline (433.176 us; speedup 1.0000x reference)
//
#include <hip/hip_runtime.h>
#include <math.h>

// ETM forward. B=1024 S=512 V=50000 E=300 H=800 T=50.
// k0: zero xbar/topicsum/loss + alpha MFMA B-frags
// kp: W1 / [Wmu|Wlv] MFMA B-frags (bf16)
// k4: betaU = exp(rho @ alpha^T) via MFMA + topicsum; emits rhoh=bf16(rho)
// k1: vocab-range-sliced token gather (16 ranges -> per-XCD L2 residency)
// k2a: xbh = bf16(xbar/n) padded K=320
// k2: hbh = bf16(relu(x@W1+b1)) via MFMA
// k3: mu/lv via MFMA -> LDS -> softmax/theta/kl
// k6: vocab-range-sliced recon + loss (betaU slice L2-resident)

#define Bn 1024
#define Sn 512
#define Vn 50000
#define En 300
#define Hn 800
#define Tn 50
#define KP 320             // padded K for E-dim (10 tiles of 32)
#define BSTR 64            // betaU bf16 row stride (ushorts) = 128 B
#define W1FRAG_N (50 * 10 * 64 * 8)
#define WFRAG_N  (8 * 25 * 64 * 8)
#define NRANGE 16
#define VRANGE (Vn / NRANGE)   // 3125 words = 1.9 MB rhoh slice per XCD L2

typedef __bf16 bf16x8 __attribute__((ext_vector_type(8)));
typedef float  f32x4  __attribute__((ext_vector_type(4)));
typedef unsigned short us8 __attribute__((ext_vector_type(8)));

__device__ __forceinline__ float waveReduceSum(float v) {
    #pragma unroll
    for (int off = 32; off > 0; off >>= 1) v += __shfl_xor(v, off, 64);
    return v;
}
__device__ __forceinline__ float waveReduceMax(float v) {
    #pragma unroll
    for (int off = 32; off > 0; off >>= 1) v = fmaxf(v, __shfl_xor(v, off, 64));
    return v;
}
__device__ __forceinline__ unsigned short f2bf(float x) {
    unsigned u = __float_as_uint(x);
    return (unsigned short)((u + 0x7FFFu + ((u >> 16) & 1u)) >> 16);
}
__device__ __forceinline__ float bf_lo(unsigned u) { return __uint_as_float(u << 16); }
__device__ __forceinline__ float bf_hi(unsigned u) { return __uint_as_float(u & 0xFFFF0000u); }

// Zero xbar/topicsum/loss; alpha B-frags (MFMA B layout).
__global__ __launch_bounds__(256) void k0_init(
        const float* __restrict__ alpha, unsigned short* __restrict__ bfrag,
        float* __restrict__ topicsum, float* __restrict__ loss,
        float* __restrict__ xbar) {
    const int gid = blockIdx.x * 256 + threadIdx.x;
    if (blockIdx.x == 0) {
        if (threadIdx.x < Tn) topicsum[threadIdx.x] = 0.f;
        if (threadIdx.x == 63) *loss = 0.f;
    }
    if (gid < Bn * En) xbar[gid] = 0.f;
    if (gid < 4 * 10 * 64 * 8) {
        int j = gid & 7;
        int lane = (gid >> 3) & 63;
        int rest = gid >> 9;               // w*10 + kt
        int kt = rest % 10, w = rest / 10;
        int t = 16 * w + (lane & 15);
        int e = kt * 32 + (lane >> 4) * 8 + j;
        bfrag[gid] = (t < Tn && e < En) ? f2bf(alpha[t * En + e]) : (unsigned short)0;
    }
}

// B-frags for W1 (50 nt x 10 kt) and [Wmu|Wlv] (8 nt x 25 kt, t>=50 zero).
__global__ __launch_bounds__(256) void kp_prep(
        const float* __restrict__ W1, const float* __restrict__ Wmu,
        const float* __restrict__ Wlv, unsigned short* __restrict__ w1frag,
        unsigned short* __restrict__ wfrag) {
    const int gid = blockIdx.x * 256 + threadIdx.x;
    if (gid < W1FRAG_N) {
        int j = gid & 7, lane = (gid >> 3) & 63, rest = gid >> 9;
        int kt = rest % 10, nt = rest / 10;
        int e = kt * 32 + (lane >> 4) * 8 + j;
        int hcol = nt * 16 + (lane & 15);
        w1frag[gid] = (e < En) ? f2bf(W1[e * Hn + hcol]) : (unsigned short)0;
    } else {
        int g2 = gid - W1FRAG_N;
        if (g2 < WFRAG_N) {
            int j = g2 & 7, lane = (g2 >> 3) & 63, rest = g2 >> 9;
            int kt = rest % 25, nt = rest / 25;
            int k = kt * 32 + (lane >> 4) * 8 + j;        // < 800 always
            int t = (nt & 3) * 16 + (lane & 15);
            float val = 0.f;
            if (t < Tn) val = (nt < 4) ? Wmu[k * Tn + t] : Wlv[k * Tn + t];
            wfrag[g2] = f2bf(val);
        }
    }
}

// betaU = exp(rho @ alpha^T) via MFMA; topicsum += sum_v; emits rhoh=bf16(rho)
// (fused cast: A-frags built from fp32 rho with guarded kt=9 tail).
__global__ __launch_bounds__(256) void k4_beta(
        const float* __restrict__ rho, const unsigned short* __restrict__ bfrag,
        unsigned int* __restrict__ betaU32, unsigned short* __restrict__ rhoh,
        float* __restrict__ topicsum) {
    __shared__ unsigned short trans[64 * 66];
    const int tid = threadIdx.x;
    const int wave = tid >> 6, lane = tid & 63;
    const int quad = lane >> 4, l15 = lane & 15;
    const int v0 = blockIdx.x * 64;

    bf16x8 bf[10];
    #pragma unroll
    for (int kt = 0; kt < 10; ++kt)
        bf[kt] = *(const bf16x8*)(bfrag + ((wave * 10 + kt) * 64 + lane) * 8);

    float ts = 0.f;
    #pragma unroll
    for (int mt = 0; mt < 4; ++mt) {
        const int vbase = v0 + mt * 16;
        int vrow = vbase + l15; if (vrow >= Vn) vrow = Vn - 1;
        const float* arow = rho + (size_t)vrow * En;
        unsigned short* hrow = rhoh + (size_t)vrow * KP;
        f32x4 acc = {0.f, 0.f, 0.f, 0.f};
        #pragma unroll
        for (int kt = 0; kt < 10; ++kt) {
            const int c0 = quad * 8 + kt * 32;
            float f[8];
            if (kt < 9) {
                float4 p = *(const float4*)(arow + c0);
                float4 q = *(const float4*)(arow + c0 + 4);
                f[0] = p.x; f[1] = p.y; f[2] = p.z; f[3] = p.w;
                f[4] = q.x; f[5] = q.y; f[6] = q.z; f[7] = q.w;
            } else {
                #pragma unroll
                for (int i = 0; i < 8; ++i)
                    f[i] = (c0 + i < En) ? arow[c0 + i] : 0.f;
            }
            us8 pk;
            #pragma unroll
            for (int i = 0; i < 8; ++i) pk[i] = f2bf(f[i]);
            *(us8*)(hrow + c0) = pk;                       // 16B aligned
            bf16x8 a = __builtin_bit_cast(bf16x8, pk);
            acc = __builtin_amdgcn_mfma_f32_16x16x32_bf16(a, bf[kt], acc, 0, 0, 0);
        }
        #pragma unroll
        for (int r = 0; r < 4; ++r) {
            int vv = vbase + quad * 4 + r;
            float ev = (vv < Vn) ? expf(acc[r]) : 0.f;
            ts += ev;
            trans[(mt * 16 + quad * 4 + r) * 66 + 16 * wave + l15] = f2bf(ev);
        }
    }
    ts += __shfl_xor(ts, 16, 64);
    ts += __shfl_xor(ts, 32, 64);
    const int t = 16 * wave + l15;
    if (lane < 16 && t < Tn) atomicAdd(&topicsum[t], ts);
    __syncthreads();
    unsigned int* dst = betaU32 + (size_t)v0 * 32;
    const unsigned int* tr32 = (const unsigned int*)trans;
    for (int i = tid; i < 64 * 32; i += 256)
        dst[i] = tr32[(i >> 5) * 33 + (i & 31)];
}

// Vocab-range-sliced gather: blk = b*16 + r handles doc b's tokens with id in
// [r*3125,(r+1)*3125) -> each XCD L2 holds a 1.9MB rhoh slice (round-robin
// dispatch heuristic; correctness mapping-independent). r==0 writes cnt[b].
__global__ __launch_bounds__(256) void k1_tokens_x(
        const int* __restrict__ ids, const unsigned int* __restrict__ rhoh32,
        int* __restrict__ cnt, float* __restrict__ xbar) {
    __shared__ int sid[Sn];
    __shared__ int scount, sfull;
    const int blk = blockIdx.x;
    const int r = blk & (NRANGE - 1), b = blk >> 4;
    const int tid = threadIdx.x;
    const int lo = r * VRANGE, hi = lo + VRANGE;
    if (tid == 0) { scount = 0; sfull = 0; }
    __syncthreads();
    #pragma unroll
    for (int s0 = 0; s0 < Sn; s0 += 256) {
        int id = ids[b * Sn + s0 + tid];
        bool val = (id != 1 && id != 2);
        if (val && id >= lo && id < hi) {
            int p = atomicAdd(&scount, 1);
            sid[p] = id;
        }
        if (r == 0 && val) atomicAdd(&sfull, 1);
    }
    __syncthreads();
    if (r == 0 && tid == 0) cnt[b] = sfull;
    const int m = scount;
    if (tid < En / 2 && m > 0) {
        float ax = 0.f, ay = 0.f;
        for (int s = 0; s < m; ++s) {
            unsigned u = rhoh32[sid[s] * (KP / 2) + tid];
            ax += bf_lo(u);
            ay += bf_hi(u);
        }
        atomicAdd(&xbar[b * En + 2 * tid], ax);
        atomicAdd(&xbar[b * En + 2 * tid + 1], ay);
    }
}

// xbh[b][e<320] = bf16(xbar[b][e]/n_b), zero pad e>=300.
__global__ __launch_bounds__(256) void k2a_xcast(
        const float* __restrict__ xbar, const int* __restrict__ cnt,
        unsigned short* __restrict__ xbh) {
    const int gid = blockIdx.x * 256 + threadIdx.x;
    if (gid < Bn * KP) {
        int b = gid / KP, e = gid - b * KP;
        unsigned short out = 0;
        if (e < En) {
            float invn = 1.0f / (float)cnt[b];
            out = f2bf(xbar[b * En + e] * invn);
        }
        xbh[gid] = out;
    }
}

// hbh = bf16(relu(x@W1+b1)) via MFMA. grid (64 mtiles, 13 nt-groups).
__global__ __launch_bounds__(256) void k2_h(
        const unsigned short* __restrict__ xbh,
        const unsigned short* __restrict__ w1frag,
        const float* __restrict__ b1, unsigned short* __restrict__ hbh) {
    const int tid = threadIdx.x;
    const int wave = tid >> 6, lane = tid & 63;
    const int quad = lane >> 4, l15 = lane & 15;
    const int b0 = blockIdx.x * 16;
    const int nt = blockIdx.y * 4 + wave;
    if (nt >= 50) return;                  // wave-uniform
    const unsigned short* arow = xbh + (size_t)(b0 + l15) * KP + quad * 8;
    f32x4 acc = {0.f, 0.f, 0.f, 0.f};
    #pragma unroll
    for (int kt = 0; kt < 10; ++kt) {
        bf16x8 a = *(const bf16x8*)(arow + kt * 32);
        bf16x8 bv = *(const bf16x8*)(w1frag + ((size_t)(nt * 10 + kt) * 64 + lane) * 8);
        acc = __builtin_amdgcn_mfma_f32_16x16x32_bf16(a, bv, acc, 0, 0, 0);
    }
    const int col = nt * 16 + l15;
    const float bias = b1[col];
    #pragma unroll
    for (int r = 0; r < 4; ++r) {
        int row = b0 + quad * 4 + r;
        hbh[(size_t)row * Hn + col] = f2bf(fmaxf(acc[r] + bias, 0.f));
    }
}

// mu/lv via MFMA -> LDS (stride 65) -> per-wave softmax/theta/kl epilogue.
__global__ __launch_bounds__(256) void k3_theta(
        const unsigned short* __restrict__ hbh,
        const unsigned short* __restrict__ wfrag,
        const float* __restrict__ bmu, const float* __restrict__ blv,
        float* __restrict__ theta, float* __restrict__ loss) {
    __shared__ float mlds[16 * 65];
    __shared__ float llds[16 * 65];
    const int tid = threadIdx.x;
    const int wave = tid >> 6, lane = tid & 63;
    const int quad = lane >> 4, l15 = lane & 15;
    const int b0 = blockIdx.x * 16;
    const unsigned short* arow = hbh + (size_t)(b0 + l15) * Hn + quad * 8;
    f32x4 am = {0.f, 0.f, 0.f, 0.f}, al = {0.f, 0.f, 0.f, 0.f};
    #pragma unroll
    for (int kt = 0; kt < 25; ++kt) {
        bf16x8 a  = *(const bf16x8*)(arow + kt * 32);
        bf16x8 bm = *(const bf16x8*)(wfrag + ((size_t)(wave * 25 + kt) * 64 + lane) * 8);
        bf16x8 bl = *(const bf16x8*)(wfrag + ((size_t)((4 + wave) * 25 + kt) * 64 + lane) * 8);
        am = __builtin_amdgcn_mfma_f32_16x16x32_bf16(a, bm, am, 0, 0, 0);
        al = __builtin_amdgcn_mfma_f32_16x16x32_bf16(a, bl, al, 0, 0, 0);
    }
    const int t = wave * 16 + l15;                 // 0..63 LDS col
    const float bm_ = (t < Tn) ? bmu[t] : 0.f;
    const float bl_ = (t < Tn) ? blv[t] : 0.f;
    #pragma unroll
    for (int r = 0; r < 4; ++r) {
        int row = quad * 4 + r;
        mlds[row * 65 + t] = am[r] + bm_;
        llds[row * 65 + t] = al[r] + bl_;
    }
    __syncthreads();
    const int tt = (lane < Tn) ? lane : (Tn - 1);
    const bool act = (lane < Tn);
    float klacc = 0.f;
    #pragma unroll
    for (int k = 0; k < 4; ++k) {
        int row = wave * 4 + k;
        float mu = mlds[row * 65 + tt];
        float lv = llds[row * 65 + tt];
        float m = waveReduceMax(act ? mu : -1e30f);
        float ex = act ? expf(mu - m) : 0.f;
        float ssum = waveReduceSum(ex);
        if (act) theta[(b0 + row) * Tn + lane] = ex / ssum;
        klacc += waveReduceSum(act ? (1.f + lv - mu * mu - expf(lv)) : 0.f);
    }
    if (lane == 0) atomicAdd(loss, -0.5f * klacc * (1.0f / (float)Bn));
}

// Vocab-range-sliced recon: blk = b*16 + r handles doc b's tokens in range r
// (betaU slice 400KB -> per-XCD L2 resident). Filters ids directly.
__global__ __launch_bounds__(256) void k6_recon(
        const int* __restrict__ ids, const float* __restrict__ theta,
        const float* __restrict__ topicsum,
        const unsigned short* __restrict__ betaUh, float* __restrict__ loss) {
    __shared__ float sw[Tn];
    __shared__ int sid[Sn];
    __shared__ int scount;
    __shared__ float swred[4];
    const int blk = blockIdx.x;
    const int r = blk & (NRANGE - 1), b = blk >> 4;
    const int tid = threadIdx.x;
    const int lo = r * VRANGE, hi = lo + VRANGE;
    if (tid < Tn) sw[tid] = theta[b * Tn + tid] / topicsum[tid];
    if (tid == 0) scount = 0;
    __syncthreads();
    #pragma unroll
    for (int s0 = 0; s0 < Sn; s0 += 256) {
        int id = ids[b * Sn + s0 + tid];
        if (id != 1 && id != 2 && id >= lo && id < hi) {
            int p = atomicAdd(&scount, 1);
            sid[p] = id;
        }
    }
    __syncthreads();
    float wr[Tn];
    #pragma unroll
    for (int t = 0; t < Tn; ++t) wr[t] = sw[t];
    float lsum = 0.f;
    const int n = scount;
    for (int i = tid; i < n; i += 256) {
        int v = sid[i];
        const uint4* q = (const uint4*)(betaUh + (size_t)v * BSTR);
        float dot = 0.f;
        #pragma unroll
        for (int k = 0; k < 6; ++k) {
            uint4 u = q[k];
            int t = 8 * k;
            dot += wr[t]     * bf_lo(u.x) + wr[t + 1] * bf_hi(u.x);
            dot += wr[t + 2] * bf_lo(u.y) + wr[t + 3] * bf_hi(u.y);
            dot += wr[t + 4] * bf_lo(u.z) + wr[t + 5] * bf_hi(u.z);
            dot += wr[t + 6] * bf_lo(u.w) + wr[t + 7] * bf_hi(u.w);
        }
        unsigned d = ((const unsigned*)q)[24];
        dot += wr[48] * bf_lo(d) + wr[49] * bf_hi(d);
        lsum += logf(dot + 1e-5f);
    }
    float s = waveReduceSum(lsum);
    const int wave = tid >> 6, lane = tid & 63;
    if (lane == 0) swred[wave] = s;
    __syncthreads();
    if (tid == 0) {
        float tot = swred[0] + swred[1] + swred[2] + swred[3];
        if (tot != 0.f) atomicAdd(loss, -tot * (1.0f / (float)Bn));
    }
}

extern "C" void kernel_launch(void* const* d_in, const int* in_sizes, int n_in,
                              void* d_out, int out_size, void* d_ws, size_t ws_size,
                              hipStream_t stream) {
    const int*   ids   = (const int*)d_in[0];
    const float* rho   = (const float*)d_in[1];
    const float* alpha = (const float*)d_in[2];
    const float* W1    = (const float*)d_in[3];
    const float* b1    = (const float*)d_in[4];
    const float* Wmu   = (const float*)d_in[5];
    const float* bmu   = (const float*)d_in[6];
    const float* Wlv   = (const float*)d_in[7];
    const float* blv   = (const float*)d_in[8];

    float* theta = (float*)d_out;            // [B, T]
    float* loss  = theta + Bn * Tn;          // scalar at d_out[51200]

    const int k4grid = (Vn + 63) / 64;                  // 782
    char* w = (char*)d_ws;
    float* topicsum = (float*)w;                w += 256;
    unsigned short* bfrag = (unsigned short*)w; w += 4 * 10 * 64 * 8 * 2;
    unsigned short* w1frag = (unsigned short*)w; w += (size_t)W1FRAG_N * 2;
    unsigned short* wfrag = (unsigned short*)w;  w += (size_t)WFRAG_N * 2;
    int*   cnt      = (int*)w;                  w += Bn * 4;
    float* xbar     = (float*)w;                w += Bn * En * 4;
    unsigned short* xbh = (unsigned short*)w;   w += (size_t)Bn * KP * 2;
    unsigned short* hbh = (unsigned short*)w;   w += (size_t)Bn * Hn * 2;
    unsigned short* rhoh = (unsigned short*)w;  w += (size_t)Vn * KP * 2;   // 32 MB
    unsigned int* betaU32 = (unsigned int*)w;   w += (size_t)k4grid * 64 * 128;

    k0_init<<<(Bn * En + 255) / 256, 256, 0, stream>>>(alpha, bfrag, topicsum, loss, xbar);
    kp_prep<<<(W1FRAG_N + WFRAG_N + 255) / 256, 256, 0, stream>>>(
        W1, Wmu, Wlv, w1frag, wfrag);
    k4_beta<<<k4grid, 256, 0, stream>>>(rho, bfrag, betaU32, rhoh, topicsum);
    k1_tokens_x<<<Bn * NRANGE, 256, 0, stream>>>(ids, (const unsigned int*)rhoh,
                                                 cnt, xbar);
    k2a_xcast<<<(Bn * KP + 255) / 256, 256, 0, stream>>>(xbar, cnt, xbh);
    k2_h<<<dim3(64, 13), 256, 0, stream>>>(xbh, w1frag, b1, hbh);
    k3_theta<<<64, 256, 0, stream>>>(hbh, wfrag, bmu, blv, theta, loss);
    k6_recon<<<Bn * NRANGE, 256, 0, stream>>>(ids, theta, topicsum,
                                              (const unsigned short*)betaU32, loss);
}

// Round 12
// 236.557 us; speedup vs baseline: 1.8312x; 1.8312x over previous
//
#include <hip/hip_runtime.h>
#include <math.h>

// ETM forward. B=1024 S=512 V=50000 E=300 H=800 T=50.
// k0: zero xbar/topicsum/loss + alpha MFMA B-frags
// kp: W1 / [Wmu|Wlv] MFMA B-frags (bf16)
// k4: betaU = exp(rho @ alpha^T) via MFMA + topicsum; emits rhoh=bf16(rho)
// k1: vocab-range-sliced token gather (8 ranges; writes toks+cnt)
// k2a: xbh = bf16(xbar/n) padded K=320
// k2: hbh = bf16(relu(x@W1+b1)) via MFMA
// k3: mu/lv via MFMA -> LDS -> softmax/theta/kl
// k6: recon + loss (one block per doc — latency-bound, do NOT slice)

#define Bn 1024
#define Sn 512
#define Vn 50000
#define En 300
#define Hn 800
#define Tn 50
#define KP 320             // padded K for E-dim (10 tiles of 32)
#define BSTR 64            // betaU bf16 row stride (ushorts) = 128 B
#define W1FRAG_N (50 * 10 * 64 * 8)
#define WFRAG_N  (8 * 25 * 64 * 8)
#define NRANGE 8
#define VRANGE (Vn / NRANGE)   // 6250 words = 3.8 MB rhoh slice

typedef __bf16 bf16x8 __attribute__((ext_vector_type(8)));
typedef float  f32x4  __attribute__((ext_vector_type(4)));
typedef unsigned short us8 __attribute__((ext_vector_type(8)));

__device__ __forceinline__ float waveReduceSum(float v) {
    #pragma unroll
    for (int off = 32; off > 0; off >>= 1) v += __shfl_xor(v, off, 64);
    return v;
}
__device__ __forceinline__ float waveReduceMax(float v) {
    #pragma unroll
    for (int off = 32; off > 0; off >>= 1) v = fmaxf(v, __shfl_xor(v, off, 64));
    return v;
}
__device__ __forceinline__ unsigned short f2bf(float x) {
    unsigned u = __float_as_uint(x);
    return (unsigned short)((u + 0x7FFFu + ((u >> 16) & 1u)) >> 16);
}
__device__ __forceinline__ float bf_lo(unsigned u) { return __uint_as_float(u << 16); }
__device__ __forceinline__ float bf_hi(unsigned u) { return __uint_as_float(u & 0xFFFF0000u); }

// Zero xbar/topicsum/loss; alpha B-frags (MFMA B layout).
__global__ __launch_bounds__(256) void k0_init(
        const float* __restrict__ alpha, unsigned short* __restrict__ bfrag,
        float* __restrict__ topicsum, float* __restrict__ loss,
        float* __restrict__ xbar) {
    const int gid = blockIdx.x * 256 + threadIdx.x;
    if (blockIdx.x == 0) {
        if (threadIdx.x < Tn) topicsum[threadIdx.x] = 0.f;
        if (threadIdx.x == 63) *loss = 0.f;
    }
    if (gid < Bn * En) xbar[gid] = 0.f;
    if (gid < 4 * 10 * 64 * 8) {
        int j = gid & 7;
        int lane = (gid >> 3) & 63;
        int rest = gid >> 9;               // w*10 + kt
        int kt = rest % 10, w = rest / 10;
        int t = 16 * w + (lane & 15);
        int e = kt * 32 + (lane >> 4) * 8 + j;
        bfrag[gid] = (t < Tn && e < En) ? f2bf(alpha[t * En + e]) : (unsigned short)0;
    }
}

// B-frags for W1 (50 nt x 10 kt) and [Wmu|Wlv] (8 nt x 25 kt, t>=50 zero).
__global__ __launch_bounds__(256) void kp_prep(
        const float* __restrict__ W1, const float* __restrict__ Wmu,
        const float* __restrict__ Wlv, unsigned short* __restrict__ w1frag,
        unsigned short* __restrict__ wfrag) {
    const int gid = blockIdx.x * 256 + threadIdx.x;
    if (gid < W1FRAG_N) {
        int j = gid & 7, lane = (gid >> 3) & 63, rest = gid >> 9;
        int kt = rest % 10, nt = rest / 10;
        int e = kt * 32 + (lane >> 4) * 8 + j;
        int hcol = nt * 16 + (lane & 15);
        w1frag[gid] = (e < En) ? f2bf(W1[e * Hn + hcol]) : (unsigned short)0;
    } else {
        int g2 = gid - W1FRAG_N;
        if (g2 < WFRAG_N) {
            int j = g2 & 7, lane = (g2 >> 3) & 63, rest = g2 >> 9;
            int kt = rest % 25, nt = rest / 25;
            int k = kt * 32 + (lane >> 4) * 8 + j;        // < 800 always
            int t = (nt & 3) * 16 + (lane & 15);
            float val = 0.f;
            if (t < Tn) val = (nt < 4) ? Wmu[k * Tn + t] : Wlv[k * Tn + t];
            wfrag[g2] = f2bf(val);
        }
    }
}

// betaU = exp(rho @ alpha^T) via MFMA; topicsum += sum_v; emits rhoh=bf16(rho)
// (fused cast: A-frags built from fp32 rho with guarded kt=9 tail).
__global__ __launch_bounds__(256) void k4_beta(
        const float* __restrict__ rho, const unsigned short* __restrict__ bfrag,
        unsigned int* __restrict__ betaU32, unsigned short* __restrict__ rhoh,
        float* __restrict__ topicsum) {
    __shared__ unsigned short trans[64 * 66];
    const int tid = threadIdx.x;
    const int wave = tid >> 6, lane = tid & 63;
    const int quad = lane >> 4, l15 = lane & 15;
    const int v0 = blockIdx.x * 64;

    bf16x8 bf[10];
    #pragma unroll
    for (int kt = 0; kt < 10; ++kt)
        bf[kt] = *(const bf16x8*)(bfrag + ((wave * 10 + kt) * 64 + lane) * 8);

    float ts = 0.f;
    #pragma unroll
    for (int mt = 0; mt < 4; ++mt) {
        const int vbase = v0 + mt * 16;
        int vrow = vbase + l15; if (vrow >= Vn) vrow = Vn - 1;
        const float* arow = rho + (size_t)vrow * En;
        unsigned short* hrow = rhoh + (size_t)vrow * KP;
        f32x4 acc = {0.f, 0.f, 0.f, 0.f};
        #pragma unroll
        for (int kt = 0; kt < 10; ++kt) {
            const int c0 = quad * 8 + kt * 32;
            float f[8];
            if (kt < 9) {
                float4 p = *(const float4*)(arow + c0);
                float4 q = *(const float4*)(arow + c0 + 4);
                f[0] = p.x; f[1] = p.y; f[2] = p.z; f[3] = p.w;
                f[4] = q.x; f[5] = q.y; f[6] = q.z; f[7] = q.w;
            } else {
                #pragma unroll
                for (int i = 0; i < 8; ++i)
                    f[i] = (c0 + i < En) ? arow[c0 + i] : 0.f;
            }
            us8 pk;
            #pragma unroll
            for (int i = 0; i < 8; ++i) pk[i] = f2bf(f[i]);
            *(us8*)(hrow + c0) = pk;                       // 16B aligned
            bf16x8 a = __builtin_bit_cast(bf16x8, pk);
            acc = __builtin_amdgcn_mfma_f32_16x16x32_bf16(a, bf[kt], acc, 0, 0, 0);
        }
        #pragma unroll
        for (int r = 0; r < 4; ++r) {
            int vv = vbase + quad * 4 + r;
            float ev = (vv < Vn) ? expf(acc[r]) : 0.f;
            ts += ev;
            trans[(mt * 16 + quad * 4 + r) * 66 + 16 * wave + l15] = f2bf(ev);
        }
    }
    ts += __shfl_xor(ts, 16, 64);
    ts += __shfl_xor(ts, 32, 64);
    const int t = 16 * wave + l15;
    if (lane < 16 && t < Tn) atomicAdd(&topicsum[t], ts);
    __syncthreads();
    unsigned int* dst = betaU32 + (size_t)v0 * 32;
    const unsigned int* tr32 = (const unsigned int*)trans;
    for (int i = tid; i < 64 * 32; i += 256)
        dst[i] = tr32[(i >> 5) * 33 + (i & 31)];
}

// Vocab-range-sliced gather (R10 known-good): blk = b*8 + r handles doc b's
// tokens with id in [r*6250,(r+1)*6250). r==0 also writes toks+cnt for k6.
__global__ __launch_bounds__(256) void k1_tokens_x(
        const int* __restrict__ ids, const unsigned int* __restrict__ rhoh32,
        int* __restrict__ toks, int* __restrict__ cnt,
        float* __restrict__ xbar) {
    __shared__ int sid[Sn];        // range-filtered tokens
    __shared__ int sfid[Sn];       // full compaction (r==0 only)
    __shared__ int scount, sfull;
    const int blk = blockIdx.x;
    const int r = blk & (NRANGE - 1), b = blk >> 3;
    const int tid = threadIdx.x;
    const int lo = r * VRANGE, hi = lo + VRANGE;
    if (tid == 0) { scount = 0; sfull = 0; }
    __syncthreads();
    #pragma unroll
    for (int s0 = 0; s0 < Sn; s0 += 256) {
        int id = ids[b * Sn + s0 + tid];
        bool val = (id != 1 && id != 2);
        if (val && id >= lo && id < hi) {
            int p = atomicAdd(&scount, 1);
            sid[p] = id;
        }
        if (r == 0 && val) {
            int p = atomicAdd(&sfull, 1);
            sfid[p] = id;
        }
    }
    __syncthreads();
    if (r == 0) {
        const int nf = sfull;
        for (int i = tid; i < nf; i += 256) toks[b * Sn + i] = sfid[i];
        if (tid == 0) cnt[b] = nf;
    }
    const int m = scount;
    if (tid < En / 2 && m > 0) {
        float ax = 0.f, ay = 0.f;
        for (int s = 0; s < m; ++s) {
            unsigned u = rhoh32[sid[s] * (KP / 2) + tid];
            ax += bf_lo(u);
            ay += bf_hi(u);
        }
        atomicAdd(&xbar[b * En + 2 * tid], ax);
        atomicAdd(&xbar[b * En + 2 * tid + 1], ay);
    }
}

// xbh[b][e<320] = bf16(xbar[b][e]/n_b), zero pad e>=300.
__global__ __launch_bounds__(256) void k2a_xcast(
        const float* __restrict__ xbar, const int* __restrict__ cnt,
        unsigned short* __restrict__ xbh) {
    const int gid = blockIdx.x * 256 + threadIdx.x;
    if (gid < Bn * KP) {
        int b = gid / KP, e = gid - b * KP;
        unsigned short out = 0;
        if (e < En) {
            float invn = 1.0f / (float)cnt[b];
            out = f2bf(xbar[b * En + e] * invn);
        }
        xbh[gid] = out;
    }
}

// hbh = bf16(relu(x@W1+b1)) via MFMA. grid (64 mtiles, 13 nt-groups).
__global__ __launch_bounds__(256) void k2_h(
        const unsigned short* __restrict__ xbh,
        const unsigned short* __restrict__ w1frag,
        const float* __restrict__ b1, unsigned short* __restrict__ hbh) {
    const int tid = threadIdx.x;
    const int wave = tid >> 6, lane = tid & 63;
    const int quad = lane >> 4, l15 = lane & 15;
    const int b0 = blockIdx.x * 16;
    const int nt = blockIdx.y * 4 + wave;
    if (nt >= 50) return;                  // wave-uniform
    const unsigned short* arow = xbh + (size_t)(b0 + l15) * KP + quad * 8;
    f32x4 acc = {0.f, 0.f, 0.f, 0.f};
    #pragma unroll
    for (int kt = 0; kt < 10; ++kt) {
        bf16x8 a = *(const bf16x8*)(arow + kt * 32);
        bf16x8 bv = *(const bf16x8*)(w1frag + ((size_t)(nt * 10 + kt) * 64 + lane) * 8);
        acc = __builtin_amdgcn_mfma_f32_16x16x32_bf16(a, bv, acc, 0, 0, 0);
    }
    const int col = nt * 16 + l15;
    const float bias = b1[col];
    #pragma unroll
    for (int r = 0; r < 4; ++r) {
        int row = b0 + quad * 4 + r;
        hbh[(size_t)row * Hn + col] = f2bf(fmaxf(acc[r] + bias, 0.f));
    }
}

// mu/lv via MFMA -> LDS (stride 65) -> per-wave softmax/theta/kl epilogue.
__global__ __launch_bounds__(256) void k3_theta(
        const unsigned short* __restrict__ hbh,
        const unsigned short* __restrict__ wfrag,
        const float* __restrict__ bmu, const float* __restrict__ blv,
        float* __restrict__ theta, float* __restrict__ loss) {
    __shared__ float mlds[16 * 65];
    __shared__ float llds[16 * 65];
    const int tid = threadIdx.x;
    const int wave = tid >> 6, lane = tid & 63;
    const int quad = lane >> 4, l15 = lane & 15;
    const int b0 = blockIdx.x * 16;
    const unsigned short* arow = hbh + (size_t)(b0 + l15) * Hn + quad * 8;
    f32x4 am = {0.f, 0.f, 0.f, 0.f}, al = {0.f, 0.f, 0.f, 0.f};
    #pragma unroll
    for (int kt = 0; kt < 25; ++kt) {
        bf16x8 a  = *(const bf16x8*)(arow + kt * 32);
        bf16x8 bm = *(const bf16x8*)(wfrag + ((size_t)(wave * 25 + kt) * 64 + lane) * 8);
        bf16x8 bl = *(const bf16x8*)(wfrag + ((size_t)((4 + wave) * 25 + kt) * 64 + lane) * 8);
        am = __builtin_amdgcn_mfma_f32_16x16x32_bf16(a, bm, am, 0, 0, 0);
        al = __builtin_amdgcn_mfma_f32_16x16x32_bf16(a, bl, al, 0, 0, 0);
    }
    const int t = wave * 16 + l15;                 // 0..63 LDS col
    const float bm_ = (t < Tn) ? bmu[t] : 0.f;
    const float bl_ = (t < Tn) ? blv[t] : 0.f;
    #pragma unroll
    for (int r = 0; r < 4; ++r) {
        int row = quad * 4 + r;
        mlds[row * 65 + t] = am[r] + bm_;
        llds[row * 65 + t] = al[r] + bl_;
    }
    __syncthreads();
    const int tt = (lane < Tn) ? lane : (Tn - 1);
    const bool act = (lane < Tn);
    float klacc = 0.f;
    #pragma unroll
    for (int k = 0; k < 4; ++k) {
        int row = wave * 4 + k;
        float mu = mlds[row * 65 + tt];
        float lv = llds[row * 65 + tt];
        float m = waveReduceMax(act ? mu : -1e30f);
        float ex = act ? expf(mu - m) : 0.f;
        float ssum = waveReduceSum(ex);
        if (act) theta[(b0 + row) * Tn + lane] = ex / ssum;
        klacc += waveReduceSum(act ? (1.f + lv - mu * mu - expf(lv)) : 0.f);
    }
    if (lane == 0) atomicAdd(loss, -0.5f * klacc * (1.0f / (float)Bn));
}

// recon[b] = -sum_tok log( sum_t (theta/Z)[t] * betaU[tok,t] + 1e-5 ).
// One block per doc (R10 known-good); betaU bf16 128B rows, uint4 loads.
__global__ __launch_bounds__(256) void k6_recon(
        const int* __restrict__ toks, const int* __restrict__ cnt,
        const float* __restrict__ theta, const float* __restrict__ topicsum,
        const unsigned short* __restrict__ betaUh, float* __restrict__ loss) {
    __shared__ float sw[Tn];
    __shared__ float swred[4];
    const int b = blockIdx.x, tid = threadIdx.x;
    if (tid < Tn) sw[tid] = theta[b * Tn + tid] / topicsum[tid];
    __syncthreads();
    float wr[Tn];
    #pragma unroll
    for (int t = 0; t < Tn; ++t) wr[t] = sw[t];
    float lsum = 0.f;
    const int n = cnt[b];
    for (int i = tid; i < n; i += 256) {
        int v = toks[b * Sn + i];
        const uint4* q = (const uint4*)(betaUh + (size_t)v * BSTR);
        float dot = 0.f;
        #pragma unroll
        for (int k = 0; k < 6; ++k) {
            uint4 u = q[k];
            int t = 8 * k;
            dot += wr[t]     * bf_lo(u.x) + wr[t + 1] * bf_hi(u.x);
            dot += wr[t + 2] * bf_lo(u.y) + wr[t + 3] * bf_hi(u.y);
            dot += wr[t + 4] * bf_lo(u.z) + wr[t + 5] * bf_hi(u.z);
            dot += wr[t + 6] * bf_lo(u.w) + wr[t + 7] * bf_hi(u.w);
        }
        unsigned d = ((const unsigned*)q)[24];
        dot += wr[48] * bf_lo(d) + wr[49] * bf_hi(d);
        lsum += logf(dot + 1e-5f);
    }
    float s = waveReduceSum(lsum);
    const int wave = tid >> 6, lane = tid & 63;
    if (lane == 0) swred[wave] = s;
    __syncthreads();
    if (tid == 0) {
        float tot = swred[0] + swred[1] + swred[2] + swred[3];
        atomicAdd(loss, -tot * (1.0f / (float)Bn));
    }
}

extern "C" void kernel_launch(void* const* d_in, const int* in_sizes, int n_in,
                              void* d_out, int out_size, void* d_ws, size_t ws_size,
                              hipStream_t stream) {
    const int*   ids   = (const int*)d_in[0];
    const float* rho   = (const float*)d_in[1];
    const float* alpha = (const float*)d_in[2];
    const float* W1    = (const float*)d_in[3];
    const float* b1    = (const float*)d_in[4];
    const float* Wmu   = (const float*)d_in[5];
    const float* bmu   = (const float*)d_in[6];
    const float* Wlv   = (const float*)d_in[7];
    const float* blv   = (const float*)d_in[8];

    float* theta = (float*)d_out;            // [B, T]
    float* loss  = theta + Bn * Tn;          // scalar at d_out[51200]

    const int k4grid = (Vn + 63) / 64;                  // 782
    char* w = (char*)d_ws;
    float* topicsum = (float*)w;                w += 256;
    unsigned short* bfrag = (unsigned short*)w; w += 4 * 10 * 64 * 8 * 2;
    unsigned short* w1frag = (unsigned short*)w; w += (size_t)W1FRAG_N * 2;
    unsigned short* wfrag = (unsigned short*)w;  w += (size_t)WFRAG_N * 2;
    int*   cnt      = (int*)w;                  w += Bn * 4;
    int*   toks     = (int*)w;                  w += Bn * Sn * 4;
    float* xbar     = (float*)w;                w += Bn * En * 4;
    unsigned short* xbh = (unsigned short*)w;   w += (size_t)Bn * KP * 2;
    unsigned short* hbh = (unsigned short*)w;   w += (size_t)Bn * Hn * 2;
    unsigned short* rhoh = (unsigned short*)w;  w += (size_t)Vn * KP * 2;   // 32 MB
    unsigned int* betaU32 = (unsigned int*)w;   w += (size_t)k4grid * 64 * 128;

    k0_init<<<(Bn * En + 255) / 256, 256, 0, stream>>>(alpha, bfrag, topicsum, loss, xbar);
    kp_prep<<<(W1FRAG_N + WFRAG_N + 255) / 256, 256, 0, stream>>>(
        W1, Wmu, Wlv, w1frag, wfrag);
    k4_beta<<<k4grid, 256, 0, stream>>>(rho, bfrag, betaU32, rhoh, topicsum);
    k1_tokens_x<<<Bn * NRANGE, 256, 0, stream>>>(ids, (const unsigned int*)rhoh,
                                                 toks, cnt, xbar);
    k2a_xcast<<<(Bn * KP + 255) / 256, 256, 0, stream>>>(xbar, cnt, xbh);
    k2_h<<<dim3(64, 13), 256, 0, stream>>>(xbh, w1frag, b1, hbh);
    k3_theta<<<64, 256, 0, stream>>>(hbh, wfrag, bmu, blv, theta, loss);
    k6_recon<<<Bn, 256, 0, stream>>>(toks, cnt, theta, topicsum,
                                     (const unsigned short*)betaU32, loss);
}

// Round 13
// 216.284 us; speedup vs baseline: 2.0028x; 1.0937x over previous
//
#include <hip/hip_runtime.h>
#include <math.h>

// ETM forward. B=1024 S=512 V=50000 E=300 H=800 T=50.
// k0: zero xbar/topicsumR/loss + alpha/W1/[Wmu|Wlv] MFMA B-frags
// k5: rhoh = bf16(rho), row-padded to K=320
// k4: betaU = exp(rhoh @ alpha^T), fine-grained (16v/block, 3125 blocks),
//     topicsum into 8 replicated banks
// k1: vocab-range-sliced token gather (8 ranges; writes toks+cnt)
// k2a: xbh = bf16(xbar/n) padded K=320
// k2: hbh = bf16(relu(x@W1+b1)) via MFMA
// k3: mu/lv via MFMA -> LDS -> softmax/theta/kl
// k6: recon + loss (one block per doc; sums topicsum replicas)

#define Bn 1024
#define Sn 512
#define Vn 50000
#define En 300
#define Hn 800
#define Tn 50
#define KP 320             // padded K for E-dim (10 tiles of 32)
#define BSTR 64            // betaU bf16 row stride (ushorts) = 128 B
#define W1FRAG_N (50 * 10 * 64 * 8)
#define WFRAG_N  (8 * 25 * 64 * 8)
#define NRANGE 8
#define VRANGE (Vn / NRANGE)   // 6250 words = 3.8 MB rhoh slice

typedef __bf16 bf16x8 __attribute__((ext_vector_type(8)));
typedef float  f32x4  __attribute__((ext_vector_type(4)));

__device__ __forceinline__ float waveReduceSum(float v) {
    #pragma unroll
    for (int off = 32; off > 0; off >>= 1) v += __shfl_xor(v, off, 64);
    return v;
}
__device__ __forceinline__ float waveReduceMax(float v) {
    #pragma unroll
    for (int off = 32; off > 0; off >>= 1) v = fmaxf(v, __shfl_xor(v, off, 64));
    return v;
}
__device__ __forceinline__ unsigned short f2bf(float x) {
    unsigned u = __float_as_uint(x);
    return (unsigned short)((u + 0x7FFFu + ((u >> 16) & 1u)) >> 16);
}
__device__ __forceinline__ float bf_lo(unsigned u) { return __uint_as_float(u << 16); }
__device__ __forceinline__ float bf_hi(unsigned u) { return __uint_as_float(u & 0xFFFF0000u); }

// Zero xbar/topicsumR(8x64)/loss; build alpha + W1 + [Wmu|Wlv] B-frags.
__global__ __launch_bounds__(256) void k0_init(
        const float* __restrict__ alpha, const float* __restrict__ W1,
        const float* __restrict__ Wmu, const float* __restrict__ Wlv,
        unsigned short* __restrict__ bfrag, unsigned short* __restrict__ w1frag,
        unsigned short* __restrict__ wfrag, float* __restrict__ topicsumR,
        float* __restrict__ loss, float* __restrict__ xbar) {
    const int gid = blockIdx.x * 256 + threadIdx.x;
    if (gid < 512) topicsumR[gid] = 0.f;
    if (gid == 520) *loss = 0.f;
    if (gid < Bn * En) xbar[gid] = 0.f;
    if (gid < 4 * 10 * 64 * 8) {
        int j = gid & 7;
        int lane = (gid >> 3) & 63;
        int rest = gid >> 9;               // w*10 + kt
        int kt = rest % 10, w = rest / 10;
        int t = 16 * w + (lane & 15);
        int e = kt * 32 + (lane >> 4) * 8 + j;
        bfrag[gid] = (t < Tn && e < En) ? f2bf(alpha[t * En + e]) : (unsigned short)0;
    }
    if (gid < W1FRAG_N) {
        int j = gid & 7, lane = (gid >> 3) & 63, rest = gid >> 9;
        int kt = rest % 10, nt = rest / 10;
        int e = kt * 32 + (lane >> 4) * 8 + j;
        int hcol = nt * 16 + (lane & 15);
        w1frag[gid] = (e < En) ? f2bf(W1[e * Hn + hcol]) : (unsigned short)0;
    } else {
        int g2 = gid - W1FRAG_N;
        if (g2 < WFRAG_N) {
            int j = g2 & 7, lane = (g2 >> 3) & 63, rest = g2 >> 9;
            int kt = rest % 25, nt = rest / 25;
            int k = kt * 32 + (lane >> 4) * 8 + j;        // < 800 always
            int t = (nt & 3) * 16 + (lane & 15);
            float val = 0.f;
            if (t < Tn) val = (nt < 4) ? Wmu[k * Tn + t] : Wlv[k * Tn + t];
            wfrag[g2] = f2bf(val);
        }
    }
}

// Streaming cast rho -> bf16 with row padding to KP.
__global__ __launch_bounds__(256) void k5_cast(
        const float4* __restrict__ rho4, ushort4* __restrict__ rhoh4) {
    const int i = blockIdx.x * 256 + threadIdx.x;
    if (i < Vn * (KP / 4)) {
        int v = i / (KP / 4), s = i - v * (KP / 4);
        ushort4 p = {0, 0, 0, 0};
        if (s < En / 4) {
            float4 r = rho4[v * (En / 4) + s];
            p.x = f2bf(r.x); p.y = f2bf(r.y); p.z = f2bf(r.z); p.w = f2bf(r.w);
        }
        rhoh4[i] = p;
    }
}

// betaU = exp(rhoh @ alpha^T) via MFMA, fine-grained: 16 v per block
// (3125 blocks, V=16*3125 exactly), wave w = topic tile w. Per wave: 10
// MFMAs. topicsum into replica blockIdx&7 (k6 sums replicas).
__global__ __launch_bounds__(256) void k4_beta(
        const unsigned short* __restrict__ rhoh,
        const unsigned short* __restrict__ bfrag,
        unsigned int* __restrict__ betaU32, float* __restrict__ topicsumR) {
    __shared__ unsigned short trans[16 * 66];   // 2112 B (dword stride 33)
    const int tid = threadIdx.x;
    const int wave = tid >> 6, lane = tid & 63;
    const int quad = lane >> 4, l15 = lane & 15;
    const int v0 = blockIdx.x * 16;

    const unsigned short* arow = rhoh + (size_t)(v0 + l15) * KP + quad * 8;
    f32x4 acc = {0.f, 0.f, 0.f, 0.f};
    #pragma unroll
    for (int kt = 0; kt < 10; ++kt) {
        bf16x8 a = *(const bf16x8*)(arow + kt * 32);
        bf16x8 bv = *(const bf16x8*)(bfrag + ((wave * 10 + kt) * 64 + lane) * 8);
        acc = __builtin_amdgcn_mfma_f32_16x16x32_bf16(a, bv, acc, 0, 0, 0);
    }
    float ts = 0.f;
    #pragma unroll
    for (int r = 0; r < 4; ++r) {
        float ev = expf(acc[r]);               // v always < Vn (exact tiling)
        ts += ev;
        trans[(quad * 4 + r) * 66 + 16 * wave + l15] = f2bf(ev);
    }
    ts += __shfl_xor(ts, 16, 64);
    ts += __shfl_xor(ts, 32, 64);              // sum over the tile's 16 v
    const int t = 16 * wave + l15;
    if (lane < 16 && t < Tn)
        atomicAdd(&topicsumR[(blockIdx.x & 7) * 64 + t], ts);
    __syncthreads();
    unsigned int* dst = betaU32 + (size_t)v0 * 32;
    const unsigned int* tr32 = (const unsigned int*)trans;
    for (int i = tid; i < 16 * 32; i += 256)
        dst[i] = tr32[(i >> 5) * 33 + (i & 31)];
}

// Vocab-range-sliced gather (R10 known-good): blk = b*8 + r handles doc b's
// tokens with id in [r*6250,(r+1)*6250). r==0 also writes toks+cnt for k6.
__global__ __launch_bounds__(256) void k1_tokens_x(
        const int* __restrict__ ids, const unsigned int* __restrict__ rhoh32,
        int* __restrict__ toks, int* __restrict__ cnt,
        float* __restrict__ xbar) {
    __shared__ int sid[Sn];        // range-filtered tokens
    __shared__ int sfid[Sn];       // full compaction (r==0 only)
    __shared__ int scount, sfull;
    const int blk = blockIdx.x;
    const int r = blk & (NRANGE - 1), b = blk >> 3;
    const int tid = threadIdx.x;
    const int lo = r * VRANGE, hi = lo + VRANGE;
    if (tid == 0) { scount = 0; sfull = 0; }
    __syncthreads();
    #pragma unroll
    for (int s0 = 0; s0 < Sn; s0 += 256) {
        int id = ids[b * Sn + s0 + tid];
        bool val = (id != 1 && id != 2);
        if (val && id >= lo && id < hi) {
            int p = atomicAdd(&scount, 1);
            sid[p] = id;
        }
        if (r == 0 && val) {
            int p = atomicAdd(&sfull, 1);
            sfid[p] = id;
        }
    }
    __syncthreads();
    if (r == 0) {
        const int nf = sfull;
        for (int i = tid; i < nf; i += 256) toks[b * Sn + i] = sfid[i];
        if (tid == 0) cnt[b] = nf;
    }
    const int m = scount;
    if (tid < En / 2 && m > 0) {
        float ax = 0.f, ay = 0.f;
        for (int s = 0; s < m; ++s) {
            unsigned u = rhoh32[sid[s] * (KP / 2) + tid];
            ax += bf_lo(u);
            ay += bf_hi(u);
        }
        atomicAdd(&xbar[b * En + 2 * tid], ax);
        atomicAdd(&xbar[b * En + 2 * tid + 1], ay);
    }
}

// xbh[b][e<320] = bf16(xbar[b][e]/n_b), zero pad e>=300.
__global__ __launch_bounds__(256) void k2a_xcast(
        const float* __restrict__ xbar, const int* __restrict__ cnt,
        unsigned short* __restrict__ xbh) {
    const int gid = blockIdx.x * 256 + threadIdx.x;
    if (gid < Bn * KP) {
        int b = gid / KP, e = gid - b * KP;
        unsigned short out = 0;
        if (e < En) {
            float invn = 1.0f / (float)cnt[b];
            out = f2bf(xbar[b * En + e] * invn);
        }
        xbh[gid] = out;
    }
}

// hbh = bf16(relu(x@W1+b1)) via MFMA. grid (64 mtiles, 13 nt-groups).
__global__ __launch_bounds__(256) void k2_h(
        const unsigned short* __restrict__ xbh,
        const unsigned short* __restrict__ w1frag,
        const float* __restrict__ b1, unsigned short* __restrict__ hbh) {
    const int tid = threadIdx.x;
    const int wave = tid >> 6, lane = tid & 63;
    const int quad = lane >> 4, l15 = lane & 15;
    const int b0 = blockIdx.x * 16;
    const int nt = blockIdx.y * 4 + wave;
    if (nt >= 50) return;                  // wave-uniform
    const unsigned short* arow = xbh + (size_t)(b0 + l15) * KP + quad * 8;
    f32x4 acc = {0.f, 0.f, 0.f, 0.f};
    #pragma unroll
    for (int kt = 0; kt < 10; ++kt) {
        bf16x8 a = *(const bf16x8*)(arow + kt * 32);
        bf16x8 bv = *(const bf16x8*)(w1frag + ((size_t)(nt * 10 + kt) * 64 + lane) * 8);
        acc = __builtin_amdgcn_mfma_f32_16x16x32_bf16(a, bv, acc, 0, 0, 0);
    }
    const int col = nt * 16 + l15;
    const float bias = b1[col];
    #pragma unroll
    for (int r = 0; r < 4; ++r) {
        int row = b0 + quad * 4 + r;
        hbh[(size_t)row * Hn + col] = f2bf(fmaxf(acc[r] + bias, 0.f));
    }
}

// mu/lv via MFMA -> LDS (stride 65) -> per-wave softmax/theta/kl epilogue.
__global__ __launch_bounds__(256) void k3_theta(
        const unsigned short* __restrict__ hbh,
        const unsigned short* __restrict__ wfrag,
        const float* __restrict__ bmu, const float* __restrict__ blv,
        float* __restrict__ theta, float* __restrict__ loss) {
    __shared__ float mlds[16 * 65];
    __shared__ float llds[16 * 65];
    const int tid = threadIdx.x;
    const int wave = tid >> 6, lane = tid & 63;
    const int quad = lane >> 4, l15 = lane & 15;
    const int b0 = blockIdx.x * 16;
    const unsigned short* arow = hbh + (size_t)(b0 + l15) * Hn + quad * 8;
    f32x4 am = {0.f, 0.f, 0.f, 0.f}, al = {0.f, 0.f, 0.f, 0.f};
    #pragma unroll
    for (int kt = 0; kt < 25; ++kt) {
        bf16x8 a  = *(const bf16x8*)(arow + kt * 32);
        bf16x8 bm = *(const bf16x8*)(wfrag + ((size_t)(wave * 25 + kt) * 64 + lane) * 8);
        bf16x8 bl = *(const bf16x8*)(wfrag + ((size_t)((4 + wave) * 25 + kt) * 64 + lane) * 8);
        am = __builtin_amdgcn_mfma_f32_16x16x32_bf16(a, bm, am, 0, 0, 0);
        al = __builtin_amdgcn_mfma_f32_16x16x32_bf16(a, bl, al, 0, 0, 0);
    }
    const int t = wave * 16 + l15;                 // 0..63 LDS col
    const float bm_ = (t < Tn) ? bmu[t] : 0.f;
    const float bl_ = (t < Tn) ? blv[t] : 0.f;
    #pragma unroll
    for (int r = 0; r < 4; ++r) {
        int row = quad * 4 + r;
        mlds[row * 65 + t] = am[r] + bm_;
        llds[row * 65 + t] = al[r] + bl_;
    }
    __syncthreads();
    const int tt = (lane < Tn) ? lane : (Tn - 1);
    const bool act = (lane < Tn);
    float klacc = 0.f;
    #pragma unroll
    for (int k = 0; k < 4; ++k) {
        int row = wave * 4 + k;
        float mu = mlds[row * 65 + tt];
        float lv = llds[row * 65 + tt];
        float m = waveReduceMax(act ? mu : -1e30f);
        float ex = act ? expf(mu - m) : 0.f;
        float ssum = waveReduceSum(ex);
        if (act) theta[(b0 + row) * Tn + lane] = ex / ssum;
        klacc += waveReduceSum(act ? (1.f + lv - mu * mu - expf(lv)) : 0.f);
    }
    if (lane == 0) atomicAdd(loss, -0.5f * klacc * (1.0f / (float)Bn));
}

// recon[b] = -sum_tok log( sum_t (theta/Z)[t] * betaU[tok,t] + 1e-5 ).
// One block per doc; Z = sum of the 8 topicsum replicas.
__global__ __launch_bounds__(256) void k6_recon(
        const int* __restrict__ toks, const int* __restrict__ cnt,
        const float* __restrict__ theta, const float* __restrict__ topicsumR,
        const unsigned short* __restrict__ betaUh, float* __restrict__ loss) {
    __shared__ float sw[Tn];
    __shared__ float swred[4];
    const int b = blockIdx.x, tid = threadIdx.x;
    if (tid < Tn) {
        float z = 0.f;
        #pragma unroll
        for (int j = 0; j < 8; ++j) z += topicsumR[j * 64 + tid];
        sw[tid] = theta[b * Tn + tid] / z;
    }
    __syncthreads();
    float wr[Tn];
    #pragma unroll
    for (int t = 0; t < Tn; ++t) wr[t] = sw[t];
    float lsum = 0.f;
    const int n = cnt[b];
    for (int i = tid; i < n; i += 256) {
        int v = toks[b * Sn + i];
        const uint4* q = (const uint4*)(betaUh + (size_t)v * BSTR);
        float dot = 0.f;
        #pragma unroll
        for (int k = 0; k < 6; ++k) {
            uint4 u = q[k];
            int t = 8 * k;
            dot += wr[t]     * bf_lo(u.x) + wr[t + 1] * bf_hi(u.x);
            dot += wr[t + 2] * bf_lo(u.y) + wr[t + 3] * bf_hi(u.y);
            dot += wr[t + 4] * bf_lo(u.z) + wr[t + 5] * bf_hi(u.z);
            dot += wr[t + 6] * bf_lo(u.w) + wr[t + 7] * bf_hi(u.w);
        }
        unsigned d = ((const unsigned*)q)[24];
        dot += wr[48] * bf_lo(d) + wr[49] * bf_hi(d);
        lsum += logf(dot + 1e-5f);
    }
    float s = waveReduceSum(lsum);
    const int wave = tid >> 6, lane = tid & 63;
    if (lane == 0) swred[wave] = s;
    __syncthreads();
    if (tid == 0) {
        float tot = swred[0] + swred[1] + swred[2] + swred[3];
        atomicAdd(loss, -tot * (1.0f / (float)Bn));
    }
}

extern "C" void kernel_launch(void* const* d_in, const int* in_sizes, int n_in,
                              void* d_out, int out_size, void* d_ws, size_t ws_size,
                              hipStream_t stream) {
    const int*   ids   = (const int*)d_in[0];
    const float* rho   = (const float*)d_in[1];
    const float* alpha = (const float*)d_in[2];
    const float* W1    = (const float*)d_in[3];
    const float* b1    = (const float*)d_in[4];
    const float* Wmu   = (const float*)d_in[5];
    const float* bmu   = (const float*)d_in[6];
    const float* Wlv   = (const float*)d_in[7];
    const float* blv   = (const float*)d_in[8];

    float* theta = (float*)d_out;            // [B, T]
    float* loss  = theta + Bn * Tn;          // scalar at d_out[51200]

    char* w = (char*)d_ws;
    float* topicsumR = (float*)w;               w += 8 * 64 * 4;
    unsigned short* bfrag = (unsigned short*)w; w += 4 * 10 * 64 * 8 * 2;
    unsigned short* w1frag = (unsigned short*)w; w += (size_t)W1FRAG_N * 2;
    unsigned short* wfrag = (unsigned short*)w;  w += (size_t)WFRAG_N * 2;
    int*   cnt      = (int*)w;                  w += Bn * 4;
    int*   toks     = (int*)w;                  w += Bn * Sn * 4;
    float* xbar     = (float*)w;                w += Bn * En * 4;
    unsigned short* xbh = (unsigned short*)w;   w += (size_t)Bn * KP * 2;
    unsigned short* hbh = (unsigned short*)w;   w += (size_t)Bn * Hn * 2;
    unsigned short* rhoh = (unsigned short*)w;  w += (size_t)Vn * KP * 2;   // 32 MB
    unsigned int* betaU32 = (unsigned int*)w;   w += (size_t)Vn * 128;      // 6.4 MB

    const int k0grid = (W1FRAG_N + WFRAG_N + 255) / 256;   // covers all branches
    k0_init<<<k0grid, 256, 0, stream>>>(alpha, W1, Wmu, Wlv, bfrag, w1frag,
                                        wfrag, topicsumR, loss, xbar);
    k5_cast<<<(Vn * (KP / 4) + 255) / 256, 256, 0, stream>>>(
        (const float4*)rho, (ushort4*)rhoh);
    k4_beta<<<Vn / 16, 256, 0, stream>>>(rhoh, bfrag, betaU32, topicsumR);
    k1_tokens_x<<<Bn * NRANGE, 256, 0, stream>>>(ids, (const unsigned int*)rhoh,
                                                 toks, cnt, xbar);
    k2a_xcast<<<(Bn * KP + 255) / 256, 256, 0, stream>>>(xbar, cnt, xbh);
    k2_h<<<dim3(64, 13), 256, 0, stream>>>(xbh, w1frag, b1, hbh);
    k3_theta<<<64, 256, 0, stream>>>(hbh, wfrag, bmu, blv, theta, loss);
    k6_recon<<<Bn, 256, 0, stream>>>(toks, cnt, theta, topicsumR,
                                     (const unsigned short*)betaU32, loss);
}

// Round 14
// 208.389 us; speedup vs baseline: 2.0787x; 1.0379x over previous
//
#include <hip/hip_runtime.h>
#include <math.h>

// ETM forward. B=1024 S=512 V=50000 E=300 H=800 T=50.
// ka: [fused] rhoh=bf16(rho) cast  +  zero xbar/topicsumR/loss + all B-frags
// kb: [fused] k4 betaU=exp(rhoh@alpha^T) (16v/block) + k1 sliced token gather
// k2m: hbh = bf16(relu((xbar/n)@W1+b1)) via MFMA (x-tile cast in LDS)
// k3: mu/lv via MFMA -> LDS -> softmax/theta/kl
// k6: recon + loss (one block per doc; sums topicsum replicas)

#define Bn 1024
#define Sn 512
#define Vn 50000
#define En 300
#define Hn 800
#define Tn 50
#define KP 320             // padded K for E-dim (10 tiles of 32)
#define BSTR 64            // betaU bf16 row stride (ushorts) = 128 B
#define W1FRAG_N (50 * 10 * 64 * 8)
#define WFRAG_N  (8 * 25 * 64 * 8)
#define NRANGE 8
#define VRANGE (Vn / NRANGE)
#define CASTB (Vn * (KP / 4) / 256)            // 15625 cast blocks
#define K4B (Vn / 16)                          // 3125 k4 blocks

typedef __bf16 bf16x8 __attribute__((ext_vector_type(8)));
typedef float  f32x4  __attribute__((ext_vector_type(4)));

__device__ __forceinline__ float waveReduceSum(float v) {
    #pragma unroll
    for (int off = 32; off > 0; off >>= 1) v += __shfl_xor(v, off, 64);
    return v;
}
__device__ __forceinline__ float waveReduceMax(float v) {
    #pragma unroll
    for (int off = 32; off > 0; off >>= 1) v = fmaxf(v, __shfl_xor(v, off, 64));
    return v;
}
__device__ __forceinline__ unsigned short f2bf(float x) {
    unsigned u = __float_as_uint(x);
    return (unsigned short)((u + 0x7FFFu + ((u >> 16) & 1u)) >> 16);
}
__device__ __forceinline__ float bf_lo(unsigned u) { return __uint_as_float(u << 16); }
__device__ __forceinline__ float bf_hi(unsigned u) { return __uint_as_float(u & 0xFFFF0000u); }

// Fused: blocks [0,CASTB) stream-cast rho->rhoh (pad to KP); the rest zero
// xbar/topicsumR/loss and build alpha/W1/[Wmu|Wlv] MFMA B-frags.
__global__ __launch_bounds__(256) void ka_init(
        const float4* __restrict__ rho4, ushort4* __restrict__ rhoh4,
        const float* __restrict__ alpha, const float* __restrict__ W1,
        const float* __restrict__ Wmu, const float* __restrict__ Wlv,
        unsigned short* __restrict__ bfrag, unsigned short* __restrict__ w1frag,
        unsigned short* __restrict__ wfrag, float* __restrict__ topicsumR,
        float* __restrict__ loss, float* __restrict__ xbar) {
    if (blockIdx.x < CASTB) {
        const int i = blockIdx.x * 256 + threadIdx.x;   // < Vn*(KP/4) exactly
        int v = i / (KP / 4), s = i - v * (KP / 4);
        ushort4 p = {0, 0, 0, 0};
        if (s < En / 4) {
            float4 r = rho4[v * (En / 4) + s];
            p.x = f2bf(r.x); p.y = f2bf(r.y); p.z = f2bf(r.z); p.w = f2bf(r.w);
        }
        rhoh4[i] = p;
        return;
    }
    const int gid = (blockIdx.x - CASTB) * 256 + threadIdx.x;
    if (gid < 512) topicsumR[gid] = 0.f;
    if (gid == 520) *loss = 0.f;
    if (gid < Bn * En) xbar[gid] = 0.f;
    if (gid < 4 * 10 * 64 * 8) {
        int j = gid & 7;
        int lane = (gid >> 3) & 63;
        int rest = gid >> 9;               // w*10 + kt
        int kt = rest % 10, w = rest / 10;
        int t = 16 * w + (lane & 15);
        int e = kt * 32 + (lane >> 4) * 8 + j;
        bfrag[gid] = (t < Tn && e < En) ? f2bf(alpha[t * En + e]) : (unsigned short)0;
    }
    if (gid < W1FRAG_N) {
        int j = gid & 7, lane = (gid >> 3) & 63, rest = gid >> 9;
        int kt = rest % 10, nt = rest / 10;
        int e = kt * 32 + (lane >> 4) * 8 + j;
        int hcol = nt * 16 + (lane & 15);
        w1frag[gid] = (e < En) ? f2bf(W1[e * Hn + hcol]) : (unsigned short)0;
    } else {
        int g2 = gid - W1FRAG_N;
        if (g2 < WFRAG_N) {
            int j = g2 & 7, lane = (g2 >> 3) & 63, rest = g2 >> 9;
            int kt = rest % 25, nt = rest / 25;
            int k = kt * 32 + (lane >> 4) * 8 + j;        // < 800 always
            int t = (nt & 3) * 16 + (lane & 15);
            float val = 0.f;
            if (t < Tn) val = (nt < 4) ? Wmu[k * Tn + t] : Wlv[k * Tn + t];
            wfrag[g2] = f2bf(val);
        }
    }
}

// Fused k4+k1: blocks [0,K4B) = betaU MFMA tiles; rest = sliced token gather.
// Co-residency overlaps k4's MFMA pipe with k1's memory latency.
__global__ __launch_bounds__(256) void kb_beta_tokens(
        const unsigned short* __restrict__ rhoh,
        const unsigned short* __restrict__ bfrag,
        unsigned int* __restrict__ betaU32, float* __restrict__ topicsumR,
        const int* __restrict__ ids, int* __restrict__ toks,
        int* __restrict__ cnt, float* __restrict__ xbar) {
    __shared__ unsigned short trans[16 * 66];   // k4 transpose (2112 B)
    __shared__ int sid[Sn];                     // k1 range-filtered tokens
    __shared__ int sfid[Sn];                    // k1 full compaction (r==0)
    __shared__ int scount, sfull;
    const int tid = threadIdx.x;

    if (blockIdx.x < K4B) {
        // ---- k4: betaU tile (16 v), wave = topic tile ----
        const int wave = tid >> 6, lane = tid & 63;
        const int quad = lane >> 4, l15 = lane & 15;
        const int v0 = blockIdx.x * 16;
        const unsigned short* arow = rhoh + (size_t)(v0 + l15) * KP + quad * 8;
        f32x4 acc = {0.f, 0.f, 0.f, 0.f};
        #pragma unroll
        for (int kt = 0; kt < 10; ++kt) {
            bf16x8 a = *(const bf16x8*)(arow + kt * 32);
            bf16x8 bv = *(const bf16x8*)(bfrag + ((wave * 10 + kt) * 64 + lane) * 8);
            acc = __builtin_amdgcn_mfma_f32_16x16x32_bf16(a, bv, acc, 0, 0, 0);
        }
        float ts = 0.f;
        #pragma unroll
        for (int r = 0; r < 4; ++r) {
            float ev = expf(acc[r]);
            ts += ev;
            trans[(quad * 4 + r) * 66 + 16 * wave + l15] = f2bf(ev);
        }
        ts += __shfl_xor(ts, 16, 64);
        ts += __shfl_xor(ts, 32, 64);
        const int t = 16 * wave + l15;
        if (lane < 16 && t < Tn)
            atomicAdd(&topicsumR[(blockIdx.x & 7) * 64 + t], ts);
        __syncthreads();
        unsigned int* dst = betaU32 + (size_t)v0 * 32;
        const unsigned int* tr32 = (const unsigned int*)trans;
        for (int i = tid; i < 16 * 32; i += 256)
            dst[i] = tr32[(i >> 5) * 33 + (i & 31)];
        return;
    }
    // ---- k1: doc-range gather ----
    const int blk = blockIdx.x - K4B;
    const int r = blk & (NRANGE - 1), b = blk >> 3;
    const int lo = r * VRANGE, hi = lo + VRANGE;
    if (tid == 0) { scount = 0; sfull = 0; }
    __syncthreads();
    #pragma unroll
    for (int s0 = 0; s0 < Sn; s0 += 256) {
        int id = ids[b * Sn + s0 + tid];
        bool val = (id != 1 && id != 2);
        if (val && id >= lo && id < hi) {
            int p = atomicAdd(&scount, 1);
            sid[p] = id;
        }
        if (r == 0 && val) {
            int p = atomicAdd(&sfull, 1);
            sfid[p] = id;
        }
    }
    __syncthreads();
    if (r == 0) {
        const int nf = sfull;
        for (int i = tid; i < nf; i += 256) toks[b * Sn + i] = sfid[i];
        if (tid == 0) cnt[b] = nf;
    }
    const int m = scount;
    const unsigned int* rhoh32 = (const unsigned int*)rhoh;
    if (tid < En / 2 && m > 0) {
        float ax = 0.f, ay = 0.f;
        for (int s = 0; s < m; ++s) {
            unsigned u = rhoh32[sid[s] * (KP / 2) + tid];
            ax += bf_lo(u);
            ay += bf_hi(u);
        }
        atomicAdd(&xbar[b * En + 2 * tid], ax);
        atomicAdd(&xbar[b * En + 2 * tid + 1], ay);
    }
}

// hbh = bf16(relu((xbar/n)@W1+b1)) via MFMA; x-tile normalized+cast into LDS
// (row stride 328 ushorts -> 2-way bank aliasing only = free).
__global__ __launch_bounds__(256) void k2m_h(
        const float* __restrict__ xbar, const int* __restrict__ cnt,
        const unsigned short* __restrict__ w1frag,
        const float* __restrict__ b1, unsigned short* __restrict__ hbh) {
    __shared__ unsigned short xs[16 * 328];    // 10496 B
    __shared__ float invn[16];
    const int tid = threadIdx.x;
    const int wave = tid >> 6, lane = tid & 63;
    const int quad = lane >> 4, l15 = lane & 15;
    const int b0 = blockIdx.x * 16;
    if (tid < 16) invn[tid] = 1.0f / (float)cnt[b0 + tid];
    __syncthreads();
    for (int i = tid; i < 16 * KP; i += 256) {
        int row = i / KP, e = i - row * KP;
        xs[row * 328 + e] = (e < En) ? f2bf(xbar[(b0 + row) * En + e] * invn[row])
                                     : (unsigned short)0;
    }
    __syncthreads();
    const int nt = blockIdx.y * 4 + wave;
    if (nt < 50) {
        const unsigned short* arow = xs + l15 * 328 + quad * 8;
        f32x4 acc = {0.f, 0.f, 0.f, 0.f};
        #pragma unroll
        for (int kt = 0; kt < 10; ++kt) {
            bf16x8 a = *(const bf16x8*)(arow + kt * 32);
            bf16x8 bv = *(const bf16x8*)(w1frag + ((size_t)(nt * 10 + kt) * 64 + lane) * 8);
            acc = __builtin_amdgcn_mfma_f32_16x16x32_bf16(a, bv, acc, 0, 0, 0);
        }
        const int col = nt * 16 + l15;
        const float bias = b1[col];
        #pragma unroll
        for (int r = 0; r < 4; ++r) {
            int row = b0 + quad * 4 + r;
            hbh[(size_t)row * Hn + col] = f2bf(fmaxf(acc[r] + bias, 0.f));
        }
    }
}

// mu/lv via MFMA -> LDS (stride 65) -> per-wave softmax/theta/kl epilogue.
__global__ __launch_bounds__(256) void k3_theta(
        const unsigned short* __restrict__ hbh,
        const unsigned short* __restrict__ wfrag,
        const float* __restrict__ bmu, const float* __restrict__ blv,
        float* __restrict__ theta, float* __restrict__ loss) {
    __shared__ float mlds[16 * 65];
    __shared__ float llds[16 * 65];
    const int tid = threadIdx.x;
    const int wave = tid >> 6, lane = tid & 63;
    const int quad = lane >> 4, l15 = lane & 15;
    const int b0 = blockIdx.x * 16;
    const unsigned short* arow = hbh + (size_t)(b0 + l15) * Hn + quad * 8;
    f32x4 am = {0.f, 0.f, 0.f, 0.f}, al = {0.f, 0.f, 0.f, 0.f};
    #pragma unroll
    for (int kt = 0; kt < 25; ++kt) {
        bf16x8 a  = *(const bf16x8*)(arow + kt * 32);
        bf16x8 bm = *(const bf16x8*)(wfrag + ((size_t)(wave * 25 + kt) * 64 + lane) * 8);
        bf16x8 bl = *(const bf16x8*)(wfrag + ((size_t)((4 + wave) * 25 + kt) * 64 + lane) * 8);
        am = __builtin_amdgcn_mfma_f32_16x16x32_bf16(a, bm, am, 0, 0, 0);
        al = __builtin_amdgcn_mfma_f32_16x16x32_bf16(a, bl, al, 0, 0, 0);
    }
    const int t = wave * 16 + l15;                 // 0..63 LDS col
    const float bm_ = (t < Tn) ? bmu[t] : 0.f;
    const float bl_ = (t < Tn) ? blv[t] : 0.f;
    #pragma unroll
    for (int r = 0; r < 4; ++r) {
        int row = quad * 4 + r;
        mlds[row * 65 + t] = am[r] + bm_;
        llds[row * 65 + t] = al[r] + bl_;
    }
    __syncthreads();
    const int tt = (lane < Tn) ? lane : (Tn - 1);
    const bool act = (lane < Tn);
    float klacc = 0.f;
    #pragma unroll
    for (int k = 0; k < 4; ++k) {
        int row = wave * 4 + k;
        float mu = mlds[row * 65 + tt];
        float lv = llds[row * 65 + tt];
        float m = waveReduceMax(act ? mu : -1e30f);
        float ex = act ? expf(mu - m) : 0.f;
        float ssum = waveReduceSum(ex);
        if (act) theta[(b0 + row) * Tn + lane] = ex / ssum;
        klacc += waveReduceSum(act ? (1.f + lv - mu * mu - expf(lv)) : 0.f);
    }
    if (lane == 0) atomicAdd(loss, -0.5f * klacc * (1.0f / (float)Bn));
}

// recon[b] = -sum_tok log( sum_t (theta/Z)[t] * betaU[tok,t] + 1e-5 ).
// One block per doc; Z = sum of the 8 topicsum replicas.
__global__ __launch_bounds__(256) void k6_recon(
        const int* __restrict__ toks, const int* __restrict__ cnt,
        const float* __restrict__ theta, const float* __restrict__ topicsumR,
        const unsigned short* __restrict__ betaUh, float* __restrict__ loss) {
    __shared__ float sw[Tn];
    __shared__ float swred[4];
    const int b = blockIdx.x, tid = threadIdx.x;
    if (tid < Tn) {
        float z = 0.f;
        #pragma unroll
        for (int j = 0; j < 8; ++j) z += topicsumR[j * 64 + tid];
        sw[tid] = theta[b * Tn + tid] / z;
    }
    __syncthreads();
    float wr[Tn];
    #pragma unroll
    for (int t = 0; t < Tn; ++t) wr[t] = sw[t];
    float lsum = 0.f;
    const int n = cnt[b];
    for (int i = tid; i < n; i += 256) {
        int v = toks[b * Sn + i];
        const uint4* q = (const uint4*)(betaUh + (size_t)v * BSTR);
        float dot = 0.f;
        #pragma unroll
        for (int k = 0; k < 6; ++k) {
            uint4 u = q[k];
            int t = 8 * k;
            dot += wr[t]     * bf_lo(u.x) + wr[t + 1] * bf_hi(u.x);
            dot += wr[t + 2] * bf_lo(u.y) + wr[t + 3] * bf_hi(u.y);
            dot += wr[t + 4] * bf_lo(u.z) + wr[t + 5] * bf_hi(u.z);
            dot += wr[t + 6] * bf_lo(u.w) + wr[t + 7] * bf_hi(u.w);
        }
        unsigned d = ((const unsigned*)q)[24];
        dot += wr[48] * bf_lo(d) + wr[49] * bf_hi(d);
        lsum += logf(dot + 1e-5f);
    }
    float s = waveReduceSum(lsum);
    const int wave = tid >> 6, lane = tid & 63;
    if (lane == 0) swred[wave] = s;
    __syncthreads();
    if (tid == 0) {
        float tot = swred[0] + swred[1] + swred[2] + swred[3];
        atomicAdd(loss, -tot * (1.0f / (float)Bn));
    }
}

extern "C" void kernel_launch(void* const* d_in, const int* in_sizes, int n_in,
                              void* d_out, int out_size, void* d_ws, size_t ws_size,
                              hipStream_t stream) {
    const int*   ids   = (const int*)d_in[0];
    const float* rho   = (const float*)d_in[1];
    const float* alpha = (const float*)d_in[2];
    const float* W1    = (const float*)d_in[3];
    const float* b1    = (const float*)d_in[4];
    const float* Wmu   = (const float*)d_in[5];
    const float* bmu   = (const float*)d_in[6];
    const float* Wlv   = (const float*)d_in[7];
    const float* blv   = (const float*)d_in[8];

    float* theta = (float*)d_out;            // [B, T]
    float* loss  = theta + Bn * Tn;          // scalar at d_out[51200]

    char* w = (char*)d_ws;
    float* topicsumR = (float*)w;               w += 8 * 64 * 4;
    unsigned short* bfrag = (unsigned short*)w; w += 4 * 10 * 64 * 8 * 2;
    unsigned short* w1frag = (unsigned short*)w; w += (size_t)W1FRAG_N * 2;
    unsigned short* wfrag = (unsigned short*)w;  w += (size_t)WFRAG_N * 2;
    int*   cnt      = (int*)w;                  w += Bn * 4;
    int*   toks     = (int*)w;                  w += Bn * Sn * 4;
    float* xbar     = (float*)w;                w += Bn * En * 4;
    unsigned short* hbh = (unsigned short*)w;   w += (size_t)Bn * Hn * 2;
    unsigned short* rhoh = (unsigned short*)w;  w += (size_t)Vn * KP * 2;   // 32 MB
    unsigned int* betaU32 = (unsigned int*)w;   w += (size_t)Vn * 128;      // 6.4 MB

    const int k0grid = (W1FRAG_N + WFRAG_N + 255) / 256;   // 1400
    ka_init<<<CASTB + k0grid, 256, 0, stream>>>(
        (const float4*)rho, (ushort4*)rhoh, alpha, W1, Wmu, Wlv,
        bfrag, w1frag, wfrag, topicsumR, loss, xbar);
    kb_beta_tokens<<<K4B + Bn * NRANGE, 256, 0, stream>>>(
        rhoh, bfrag, betaU32, topicsumR, ids, toks, cnt, xbar);
    k2m_h<<<dim3(64, 13), 256, 0, stream>>>(xbar, cnt, w1frag, b1, hbh);
    k3_theta<<<64, 256, 0, stream>>>(hbh, wfrag, bmu, blv, theta, loss);
    k6_recon<<<Bn, 256, 0, stream>>>(toks, cnt, theta, topicsumR,
                                     (const unsigned short*)betaU32, loss);
}